// Round 1
// baseline (1110.486 us; speedup 1.0000x reference)
//
#include <hip/hip_runtime.h>

#define T_LEN 4096
#define B_SZ  256

typedef float v2f __attribute__((ext_vector_type(2)));
typedef float v4f __attribute__((ext_vector_type(4)));

__device__ __forceinline__ float fexp2(float x) { return __builtin_amdgcn_exp2f(x); }
__device__ __forceinline__ float frcp(float x)  { return __builtin_amdgcn_rcpf(x); }

// DPP row_ror:S (S=1..15): lane l <- lane (l-S)&15 within its 16-lane row.
template<int S>
__device__ __forceinline__ float rorN(float v) {
    return __int_as_float(__builtin_amdgcn_update_dpp(
        0, __float_as_int(v), 0x120 + S, 0xf, 0xf, true));
}

// Inline-asm vm ops: the register allocator cannot rematerialize an asm
// result (round-5/6 VGPR=88..92 proved RA re-emits plain loads at their
// uses, exposing full memory latency every macro), and with an all-asm vm
// stream the outstanding-op counts for manual s_waitcnt are exact.
template<int OFF>
__device__ __forceinline__ v4f aload(const float* p) {
    v4f r;
    asm volatile("global_load_dwordx4 %0, %1, off offset:%2"
                 : "=v"(r) : "v"(p), "i"(OFF) : "memory");
    return r;
}
__device__ __forceinline__ void aatomic(float* p, float v) {
    asm volatile("global_atomic_add_f32 %0, %1, off"
                 :: "v"(p), "v"(v) : "memory");
}

// ---------------------------------------------------------------------------
// Init: y1 <- bl1 broadcast, out <- bl2 broadcast. Recurrent kernels
// atomic-add their projected h contributions on top.
// ---------------------------------------------------------------------------
__global__ void init_bias_kernel(const float* __restrict__ bl1,
                                 const float* __restrict__ bl2,
                                 float* __restrict__ y1,
                                 float* __restrict__ out)
{
    const long idx = (long)blockIdx.x * blockDim.x + threadIdx.x; // over B*T
    float4 a1 = make_float4(bl1[0], bl1[1], bl1[2], bl1[3]);
    float4 b1 = make_float4(bl1[4], bl1[5], bl1[6], bl1[7]);
    float4 a2 = make_float4(bl2[0], bl2[1], bl2[2], bl2[3]);
    float4 b2 = make_float4(bl2[4], bl2[5], bl2[6], bl2[7]);
    float4* y4 = (float4*)y1;
    float4* o4 = (float4*)out;
    y4[idx * 2 + 0] = a1;
    y4[idx * 2 + 1] = b1;
    o4[idx * 2 + 0] = a2;
    o4[idx * 2 + 1] = b2;
}

// ---------------------------------------------------------------------------
// Recurrence, one direction (ST=+1 fwd / -1 bwd). 16 lanes per cell, 4 cells
// per wave, 128 blocks x 64 threads. Lane cl: unit j=cl&7, half=cl>>3.
// Each lane computes TWO gate rows packed <2 x float>: half0 -> (i_j, f_j),
// half1 -> (g_j, o_j). h is period-8 replicated over the 16-lane row; DPP
// row_ror does the h broadcast (no LDS/DS on the chain). x arrives through
// an asm-load register ring (3 macros of 4 steps), lookahead 2 macros, with
// exact manual s_waitcnt vmcnt(N). Output projection fused as asm
// global_atomic_add_f32 of h_{t-1} from all lanes (Wc pre-halved; the two
// halves contribute pa/2 each).
//
// Chain-depth version (this round): track sc = GSC*c (kills the c*GSC mul
// before tanh's exp2; GSC folds into half0's activation fma which was a
// wasted identity), compute i*g as vA*ror8(vA) (same product on both
// halves -> no cndmask on the P path), and run the hidden matvec as 4
// depth-2 fma chains (two seeded with split input-projection partials)
// + a depth-2 add tree (z at depth 5 from h instead of 6).
// Serial c->c chain: 20 -> 17 dependent VALU ops.
// ---------------------------------------------------------------------------
template<int ST>
__device__ __forceinline__ void rec_body(
    const float* x,    // [B,T,8] layer input
    const float* Wih,  // [32,8]
    const float* Whh,  // [32,8]
    const float* bias, // [32]
    const float* Wp,   // [8,16] output linear
    int dcol,          // 0 fwd, 8 bwd
    float* y,          // [B,T,8], pre-inited with bias
    int b0)            // batch of first cell in this wave
{
    const int tid  = threadIdx.x;
    const int cl   = tid & 15;
    const int j    = cl & 7;
    const int half = cl >> 3;
    const int b    = b0 + (tid >> 4);

    const int rA = half * 16 + j;        // half0: i-row j   | half1: g-row 16+j
    const int rB = half * 16 + 8 + j;    // half0: f-row 8+j | half1: o-row 24+j

    const float NL2E = -1.4426950408889634f;
    const float GSC  = 2.0f * NL2E;
    const float sA   = half ? GSC : NL2E;     // g-row gets tanh pre-scale
    const float sB   = NL2E;
    // half0 vA = GSC*sigma(zi) (i pre-scaled for the sc-space c update);
    // half1 vA = tanh-core 2*sigma(2zg)-1
    const float aselA = half ? 2.0f : GSC;
    const float bselA = half ? -1.0f : 0.0f;

    // Per-lane constants: matvec weights permuted by rotation index.
    v2f Whk[8], Wik[8];
    float Wcp[8];
    #pragma unroll
    for (int s = 0; s < 8; ++s) {
        const int k = (j - s) & 7;
        Whk[s] = (v2f){Whh[rA * 8 + k] * sA, Whh[rB * 8 + k] * sB};
        Wcp[s] = Wp[j * 16 + dcol + k] * 0.5f;  // halved: both halves atomic
    }
    #pragma unroll
    for (int k = 0; k < 8; ++k)
        Wik[k] = (v2f){Wih[rA * 8 + k] * sA, Wih[rB * 8 + k] * sB};
    const v2f bpk = (v2f){bias[rA] * sA, bias[rB] * sB};

    const int start = (ST > 0) ? 0 : (T_LEN - 1);
    const float* xp = x + ((long)b * T_LEN + start) * 8;
    float*       wp = y + ((long)b * T_LEN + start) * 8 + j;

    float sc = 0.0f, h = 0.0f;   // sc = GSC * c

    auto step = [&](v4f xa, v4f xb, bool doProj) {
        // input projection partials, two independent seeds (no h dependence;
        // fills issue while h settles). Never merged: they seed two of the
        // four hidden-matvec chains.
        v2f ipA = bpk;
        ipA = __builtin_elementwise_fma(Wik[0], (v2f){xa.x, xa.x}, ipA);
        ipA = __builtin_elementwise_fma(Wik[1], (v2f){xa.y, xa.y}, ipA);
        ipA = __builtin_elementwise_fma(Wik[2], (v2f){xa.z, xa.z}, ipA);
        ipA = __builtin_elementwise_fma(Wik[3], (v2f){xa.w, xa.w}, ipA);
        v2f ipB = Wik[4] * (v2f){xb.x, xb.x};
        ipB = __builtin_elementwise_fma(Wik[5], (v2f){xb.y, xb.y}, ipB);
        ipB = __builtin_elementwise_fma(Wik[6], (v2f){xb.z, xb.z}, ipB);
        ipB = __builtin_elementwise_fma(Wik[7], (v2f){xb.w, xb.w}, ipB);

        // 7 independent VALU rotations of h (h_{t-1})
        float hr0 = h;
        float hr1 = rorN<1>(h);
        float hr2 = rorN<2>(h);
        float hr3 = rorN<3>(h);
        float hr4 = rorN<4>(h);
        float hr5 = rorN<5>(h);
        float hr6 = rorN<6>(h);
        float hr7 = rorN<7>(h);

        // hidden matvec: 4 depth-2 chains + depth-2 add tree (z@5 from h)
        v2f cA = __builtin_elementwise_fma(Whk[0], (v2f){hr0, hr0}, ipA);
        cA = __builtin_elementwise_fma(Whk[1], (v2f){hr1, hr1}, cA);
        v2f cB = __builtin_elementwise_fma(Whk[2], (v2f){hr2, hr2}, ipB);
        cB = __builtin_elementwise_fma(Whk[3], (v2f){hr3, hr3}, cB);
        v2f cC = Whk[4] * (v2f){hr4, hr4};
        cC = __builtin_elementwise_fma(Whk[5], (v2f){hr5, hr5}, cC);
        v2f cD = Whk[6] * (v2f){hr6, hr6};
        cD = __builtin_elementwise_fma(Whk[7], (v2f){hr7, hr7}, cD);
        const v2f z = (cA + cB) + (cC + cD);

        // fused output projection of h_{t-1} (off-chain); all 64 lanes
        // atomic with halved Wcp (two halves sum to the full contribution)
        if (doProj) {
            float pa = hr0 * Wcp[0];
            pa = fmaf(hr1, Wcp[1], pa);
            pa = fmaf(hr2, Wcp[2], pa);
            pa = fmaf(hr3, Wcp[3], pa);
            pa = fmaf(hr4, Wcp[4], pa);
            pa = fmaf(hr5, Wcp[5], pa);
            pa = fmaf(hr6, Wcp[6], pa);
            pa = fmaf(hr7, Wcp[7], pa);
            aatomic(wp, pa);
            wp += ST * 8;
        }

        // activations: half0 vA = GSC*sigma(zi), half1 vA = tanh(zg);
        //              half0 vB = sigma(zf),     half1 vB = sigma(zo)
        const float vA = fmaf(frcp(1.0f + fexp2(z.x)), aselA, bselA);
        const float vB = frcp(1.0f + fexp2(z.y));

        // cross-half gate exchange (row_ror:8 swaps the two 8-lane halves);
        // i*g product is vA*ror8(vA) on BOTH halves (no select needed)
        const float pAx = rorN<8>(vA);
        const float pBx = rorN<8>(vB);
        const float gf = half ? pBx : vB;
        const float go = half ? vB  : pBx;

        sc = fmaf(gf, sc, vA * pAx);            // sc = GSC * c
        const float th = fmaf(frcp(1.0f + fexp2(sc)), 2.0f, -1.0f);
        h = go * th;
    };

    // Named prefetch ring: 3 macros x 4 steps (2 x v4f per step).
    v4f A0, A1, A2, A3, A4, A5, A6, A7;
    v4f B0, B1, B2, B3, B4, B5, B6, B7;
    v4f C0, C1, C2, C3, C4, C5, C6, C7;

#define AREGS A0, A1, A2, A3, A4, A5, A6, A7
#define BREGS B0, B1, B2, B3, B4, B5, B6, B7
#define CREGS C0, C1, C2, C3, C4, C5, C6, C7

// Inner 8-parameter macros + one indirection layer so that a register-set
// macro (AREGS/BREGS/CREGS) expands to 8 arguments before re-scanning.
#define LOADM_I(P0, P1, P2, P3, P4, P5, P6, P7)                                \
    P0 = aload<0>(xp);            P1 = aload<16>(xp);                          \
    P2 = aload<ST * 32>(xp);      P3 = aload<ST * 32 + 16>(xp);                \
    P4 = aload<ST * 64>(xp);      P5 = aload<ST * 64 + 16>(xp);                \
    P6 = aload<ST * 96>(xp);      P7 = aload<ST * 96 + 16>(xp);                \
    xp += ST * 32;
#define LOADM(REGS) LOADM_I(REGS)

#define WAITM_I(N, P0, P1, P2, P3, P4, P5, P6, P7)                             \
    asm volatile("s_waitcnt vmcnt(" #N ")"                                     \
        : "+v"(P0), "+v"(P1), "+v"(P2), "+v"(P3),                              \
          "+v"(P4), "+v"(P5), "+v"(P6), "+v"(P7) :: "memory")
#define WAITM(N, REGS) WAITM_I(N, REGS)

#define MACRO4_I(P0, P1, P2, P3, P4, P5, P6, P7, FIRSTPROJ)                    \
    step(P0, P1, FIRSTPROJ);                                                   \
    step(P2, P3, true);                                                        \
    step(P4, P5, true);                                                        \
    step(P6, P7, true);
#define MACRO4(REGS, FIRSTPROJ) MACRO4_I(REGS, FIRSTPROJ)

    // drain compiler-issued (weight) loads so asm vm counts are exact
    asm volatile("s_waitcnt vmcnt(0)" ::: "memory");

    LOADM(AREGS)                       // L0
    LOADM(BREGS)                       // L1
    LOADM(CREGS)                       // L2
    WAITM(16, AREGS); MACRO4(AREGS, false)    // M0 (3 atomics: h_{-1}=0)
    LOADM(AREGS)                       // L3
    WAITM(19, BREGS); MACRO4(BREGS, true)     // M1 (4 atomics)
    LOADM(BREGS)                       // L4
    WAITM(23, CREGS); MACRO4(CREGS, true)     // M2

    for (int i = 0; i < 339; ++i) {    // M3..M1019, loads L5..L1021
        LOADM(CREGS) WAITM(24, AREGS); MACRO4(AREGS, true)
        LOADM(AREGS) WAITM(24, BREGS); MACRO4(BREGS, true)
        LOADM(BREGS) WAITM(24, CREGS); MACRO4(CREGS, true)
    }
    LOADM(CREGS)                       // L1022
    WAITM(24, AREGS); MACRO4(AREGS, true)     // M1020
    LOADM(AREGS)                       // L1023
    WAITM(24, BREGS); MACRO4(BREGS, true)     // M1021
    WAITM(16, CREGS); MACRO4(CREGS, true)     // M1022
    WAITM(8,  AREGS); MACRO4(AREGS, true)     // M1023

#undef LOADM
#undef LOADM_I
#undef MACRO4
#undef MACRO4_I
#undef WAITM
#undef WAITM_I
#undef AREGS
#undef BREGS
#undef CREGS

    // tail: projection of the final h (all lanes, halved Wcp)
    {
        float pa = h * Wcp[0];
        pa = fmaf(rorN<1>(h), Wcp[1], pa);
        pa = fmaf(rorN<2>(h), Wcp[2], pa);
        pa = fmaf(rorN<3>(h), Wcp[3], pa);
        pa = fmaf(rorN<4>(h), Wcp[4], pa);
        pa = fmaf(rorN<5>(h), Wcp[5], pa);
        pa = fmaf(rorN<6>(h), Wcp[6], pa);
        pa = fmaf(rorN<7>(h), Wcp[7], pa);
        aatomic(wp, pa);
    }
}

__global__ __launch_bounds__(64, 1)
void lstm_rec_kernel(const float* __restrict__ x,
                     const float* __restrict__ WihF, const float* __restrict__ WhhF,
                     const float* __restrict__ bF,
                     const float* __restrict__ WihB, const float* __restrict__ WhhB,
                     const float* __restrict__ bB,
                     const float* __restrict__ Wp,
                     float* __restrict__ y)
{
    if (blockIdx.x < 64)
        rec_body<1 >(x, WihF, WhhF, bF, Wp, 0, y, 4 * (int)blockIdx.x);
    else
        rec_body<-1>(x, WihB, WhhB, bB, Wp, 8, y, 4 * ((int)blockIdx.x - 64));
}

extern "C" void kernel_launch(void* const* d_in, const int* in_sizes, int n_in,
                              void* d_out, int out_size, void* d_ws, size_t ws_size,
                              hipStream_t stream)
{
    const float* x     = (const float*)d_in[0];
    const float* Wih1f = (const float*)d_in[1];
    const float* Whh1f = (const float*)d_in[2];
    const float* b1f   = (const float*)d_in[3];
    const float* Wih1b = (const float*)d_in[4];
    const float* Whh1b = (const float*)d_in[5];
    const float* b1b   = (const float*)d_in[6];
    const float* Wih2f = (const float*)d_in[7];
    const float* Whh2f = (const float*)d_in[8];
    const float* b2f   = (const float*)d_in[9];
    const float* Wih2b = (const float*)d_in[10];
    const float* Whh2b = (const float*)d_in[11];
    const float* b2b   = (const float*)d_in[12];
    const float* W1    = (const float*)d_in[13];
    const float* bl1   = (const float*)d_in[14];
    const float* W2    = (const float*)d_in[15];
    const float* bl2   = (const float*)d_in[16];

    float* out = (float*)d_out;
    float* y1  = (float*)d_ws;   // [B,T,8] fp32 = 32 MB (proven-safe ws budget)

    const int BT = B_SZ * T_LEN;

    init_bias_kernel<<<BT / 256, 256, 0, stream>>>(bl1, bl2, y1, out);

    lstm_rec_kernel<<<128, 64, 0, stream>>>(x, Wih1f, Whh1f, b1f,
                                            Wih1b, Whh1b, b1b, W1, y1);

    lstm_rec_kernel<<<128, 64, 0, stream>>>(y1, Wih2f, Whh2f, b2f,
                                            Wih2b, Whh2b, b2b, W2, out);
}

// Round 2
// 1098.872 us; speedup vs baseline: 1.0106x; 1.0106x over previous
//
#include <hip/hip_runtime.h>

#define T_LEN 4096
#define B_SZ  256

typedef float v2f __attribute__((ext_vector_type(2)));
typedef float v4f __attribute__((ext_vector_type(4)));

__device__ __forceinline__ float fexp2(float x) { return __builtin_amdgcn_exp2f(x); }
__device__ __forceinline__ float frcp(float x)  { return __builtin_amdgcn_rcpf(x); }

// DPP row_ror:S (S=1..15): lane l <- lane (l-S)&15 within its 16-lane row.
template<int S>
__device__ __forceinline__ float rorN(float v) {
    return __int_as_float(__builtin_amdgcn_update_dpp(
        0, __float_as_int(v), 0x120 + S, 0xf, 0xf, true));
}

// Inline-asm LOADS stay asm: the register allocator cannot rematerialize an
// asm result (round-5/6 VGPR=88..92 proved RA re-emits plain loads at their
// uses, exposing full memory latency every macro), and the asm vm stream
// keeps the outstanding-op counts for manual s_waitcnt exact.
//
// The ATOMIC is now a plain compiler atomic (unsafeAtomicAdd ->
// global_atomic_add_f32, no-return). Rationale: volatile asm is a
// scheduling-REGION BOUNDARY for LLVM's machine scheduler; one asm atomic
// per step chopped every step into tiny regions, so step t+1's independent
// input-projection could never be interleaved into step t's transcendental
// stall window (measured: VALUBusy 10% = ~118 issue cyc vs 295 cyc/step).
// An atomic has no result, so the load-rematerialization hazard does not
// apply. It still cannot cross the volatile WAITM asm ("memory" clobber),
// so the per-macro vm-op count (8 loads + 4 atomics) and the hand-tuned
// vmcnt(24) semantics are unchanged.
template<int OFF>
__device__ __forceinline__ v4f aload(const float* p) {
    v4f r;
    asm volatile("global_load_dwordx4 %0, %1, off offset:%2"
                 : "=v"(r) : "v"(p), "i"(OFF) : "memory");
    return r;
}
__device__ __forceinline__ void aatomic(float* p, float v) {
    unsafeAtomicAdd(p, v);   // global_atomic_add_f32, no-return (result dead)
}

// ---------------------------------------------------------------------------
// Init: y1 <- bl1 broadcast, out <- bl2 broadcast. Recurrent kernels
// atomic-add their projected h contributions on top.
// ---------------------------------------------------------------------------
__global__ void init_bias_kernel(const float* __restrict__ bl1,
                                 const float* __restrict__ bl2,
                                 float* __restrict__ y1,
                                 float* __restrict__ out)
{
    const long idx = (long)blockIdx.x * blockDim.x + threadIdx.x; // over B*T
    float4 a1 = make_float4(bl1[0], bl1[1], bl1[2], bl1[3]);
    float4 b1 = make_float4(bl1[4], bl1[5], bl1[6], bl1[7]);
    float4 a2 = make_float4(bl2[0], bl2[1], bl2[2], bl2[3]);
    float4 b2 = make_float4(bl2[4], bl2[5], bl2[6], bl2[7]);
    float4* y4 = (float4*)y1;
    float4* o4 = (float4*)out;
    y4[idx * 2 + 0] = a1;
    y4[idx * 2 + 1] = b1;
    o4[idx * 2 + 0] = a2;
    o4[idx * 2 + 1] = b2;
}

// ---------------------------------------------------------------------------
// Recurrence, one direction (ST=+1 fwd / -1 bwd). 16 lanes per cell, 4 cells
// per wave, 128 blocks x 64 threads. Lane cl: unit j=cl&7, half=cl>>3.
// Each lane computes TWO gate rows packed <2 x float>: half0 -> (i_j, f_j),
// half1 -> (g_j, o_j). h is period-8 replicated over the 16-lane row; DPP
// row_ror does the h broadcast (no LDS/DS on the chain). x arrives through
// an asm-load register ring (3 macros of 4 steps), lookahead 2 macros, with
// exact manual s_waitcnt vmcnt(N). Output projection fused as
// global_atomic_add_f32 of h_{t-1} from all lanes (Wc pre-halved; the two
// halves contribute pa/2 each).
//
// sc = GSC*c tracking, i*g = vA*ror8(vA), 4x depth-2 matvec chains (R1).
// ---------------------------------------------------------------------------
template<int ST>
__device__ __forceinline__ void rec_body(
    const float* x,    // [B,T,8] layer input
    const float* Wih,  // [32,8]
    const float* Whh,  // [32,8]
    const float* bias, // [32]
    const float* Wp,   // [8,16] output linear
    int dcol,          // 0 fwd, 8 bwd
    float* y,          // [B,T,8], pre-inited with bias
    int b0)            // batch of first cell in this wave
{
    const int tid  = threadIdx.x;
    const int cl   = tid & 15;
    const int j    = cl & 7;
    const int half = cl >> 3;
    const int b    = b0 + (tid >> 4);

    const int rA = half * 16 + j;        // half0: i-row j   | half1: g-row 16+j
    const int rB = half * 16 + 8 + j;    // half0: f-row 8+j | half1: o-row 24+j

    const float NL2E = -1.4426950408889634f;
    const float GSC  = 2.0f * NL2E;
    const float sA   = half ? GSC : NL2E;     // g-row gets tanh pre-scale
    const float sB   = NL2E;
    // half0 vA = GSC*sigma(zi) (i pre-scaled for the sc-space c update);
    // half1 vA = tanh-core 2*sigma(2zg)-1
    const float aselA = half ? 2.0f : GSC;
    const float bselA = half ? -1.0f : 0.0f;

    // Per-lane constants: matvec weights permuted by rotation index.
    v2f Whk[8], Wik[8];
    float Wcp[8];
    #pragma unroll
    for (int s = 0; s < 8; ++s) {
        const int k = (j - s) & 7;
        Whk[s] = (v2f){Whh[rA * 8 + k] * sA, Whh[rB * 8 + k] * sB};
        Wcp[s] = Wp[j * 16 + dcol + k] * 0.5f;  // halved: both halves atomic
    }
    #pragma unroll
    for (int k = 0; k < 8; ++k)
        Wik[k] = (v2f){Wih[rA * 8 + k] * sA, Wih[rB * 8 + k] * sB};
    const v2f bpk = (v2f){bias[rA] * sA, bias[rB] * sB};

    const int start = (ST > 0) ? 0 : (T_LEN - 1);
    const float* xp = x + ((long)b * T_LEN + start) * 8;
    float*       wp = y + ((long)b * T_LEN + start) * 8 + j;

    float sc = 0.0f, h = 0.0f;   // sc = GSC * c

    auto step = [&](v4f xa, v4f xb, bool doProj) {
        // input projection partials, two independent seeds (no h dependence;
        // fills issue while h settles). Never merged: they seed two of the
        // four hidden-matvec chains.
        v2f ipA = bpk;
        ipA = __builtin_elementwise_fma(Wik[0], (v2f){xa.x, xa.x}, ipA);
        ipA = __builtin_elementwise_fma(Wik[1], (v2f){xa.y, xa.y}, ipA);
        ipA = __builtin_elementwise_fma(Wik[2], (v2f){xa.z, xa.z}, ipA);
        ipA = __builtin_elementwise_fma(Wik[3], (v2f){xa.w, xa.w}, ipA);
        v2f ipB = Wik[4] * (v2f){xb.x, xb.x};
        ipB = __builtin_elementwise_fma(Wik[5], (v2f){xb.y, xb.y}, ipB);
        ipB = __builtin_elementwise_fma(Wik[6], (v2f){xb.z, xb.z}, ipB);
        ipB = __builtin_elementwise_fma(Wik[7], (v2f){xb.w, xb.w}, ipB);

        // 7 independent VALU rotations of h (h_{t-1})
        float hr0 = h;
        float hr1 = rorN<1>(h);
        float hr2 = rorN<2>(h);
        float hr3 = rorN<3>(h);
        float hr4 = rorN<4>(h);
        float hr5 = rorN<5>(h);
        float hr6 = rorN<6>(h);
        float hr7 = rorN<7>(h);

        // hidden matvec: 4 depth-2 chains + depth-2 add tree (z@5 from h)
        v2f cA = __builtin_elementwise_fma(Whk[0], (v2f){hr0, hr0}, ipA);
        cA = __builtin_elementwise_fma(Whk[1], (v2f){hr1, hr1}, cA);
        v2f cB = __builtin_elementwise_fma(Whk[2], (v2f){hr2, hr2}, ipB);
        cB = __builtin_elementwise_fma(Whk[3], (v2f){hr3, hr3}, cB);
        v2f cC = Whk[4] * (v2f){hr4, hr4};
        cC = __builtin_elementwise_fma(Whk[5], (v2f){hr5, hr5}, cC);
        v2f cD = Whk[6] * (v2f){hr6, hr6};
        cD = __builtin_elementwise_fma(Whk[7], (v2f){hr7, hr7}, cD);
        const v2f z = (cA + cB) + (cC + cD);

        // fused output projection of h_{t-1} (off-chain; hr0..7 are ready at
        // step start, so with a merged scheduling region this can slot into
        // the activation-chain stall window); all 64 lanes atomic with
        // halved Wcp (two halves sum to the full contribution)
        if (doProj) {
            float pa = hr0 * Wcp[0];
            pa = fmaf(hr1, Wcp[1], pa);
            pa = fmaf(hr2, Wcp[2], pa);
            pa = fmaf(hr3, Wcp[3], pa);
            pa = fmaf(hr4, Wcp[4], pa);
            pa = fmaf(hr5, Wcp[5], pa);
            pa = fmaf(hr6, Wcp[6], pa);
            pa = fmaf(hr7, Wcp[7], pa);
            aatomic(wp, pa);
            wp += ST * 8;
        }

        // activations: half0 vA = GSC*sigma(zi), half1 vA = tanh(zg);
        //              half0 vB = sigma(zf),     half1 vB = sigma(zo)
        const float vA = fmaf(frcp(1.0f + fexp2(z.x)), aselA, bselA);
        const float vB = frcp(1.0f + fexp2(z.y));

        // cross-half gate exchange (row_ror:8 swaps the two 8-lane halves);
        // i*g product is vA*ror8(vA) on BOTH halves (no select needed)
        const float pAx = rorN<8>(vA);
        const float pBx = rorN<8>(vB);
        const float gf = half ? pBx : vB;
        const float go = half ? vB  : pBx;

        sc = fmaf(gf, sc, vA * pAx);            // sc = GSC * c
        const float th = fmaf(frcp(1.0f + fexp2(sc)), 2.0f, -1.0f);
        h = go * th;
    };

    // Named prefetch ring: 3 macros x 4 steps (2 x v4f per step).
    v4f A0, A1, A2, A3, A4, A5, A6, A7;
    v4f B0, B1, B2, B3, B4, B5, B6, B7;
    v4f C0, C1, C2, C3, C4, C5, C6, C7;

#define AREGS A0, A1, A2, A3, A4, A5, A6, A7
#define BREGS B0, B1, B2, B3, B4, B5, B6, B7
#define CREGS C0, C1, C2, C3, C4, C5, C6, C7

// Inner 8-parameter macros + one indirection layer so that a register-set
// macro (AREGS/BREGS/CREGS) expands to 8 arguments before re-scanning.
#define LOADM_I(P0, P1, P2, P3, P4, P5, P6, P7)                                \
    P0 = aload<0>(xp);            P1 = aload<16>(xp);                          \
    P2 = aload<ST * 32>(xp);      P3 = aload<ST * 32 + 16>(xp);                \
    P4 = aload<ST * 64>(xp);      P5 = aload<ST * 64 + 16>(xp);                \
    P6 = aload<ST * 96>(xp);      P7 = aload<ST * 96 + 16>(xp);                \
    xp += ST * 32;
#define LOADM(REGS) LOADM_I(REGS)

#define WAITM_I(N, P0, P1, P2, P3, P4, P5, P6, P7)                             \
    asm volatile("s_waitcnt vmcnt(" #N ")"                                     \
        : "+v"(P0), "+v"(P1), "+v"(P2), "+v"(P3),                              \
          "+v"(P4), "+v"(P5), "+v"(P6), "+v"(P7) :: "memory")
#define WAITM(N, REGS) WAITM_I(N, REGS)

#define MACRO4_I(P0, P1, P2, P3, P4, P5, P6, P7, FIRSTPROJ)                    \
    step(P0, P1, FIRSTPROJ);                                                   \
    step(P2, P3, true);                                                        \
    step(P4, P5, true);                                                        \
    step(P6, P7, true);
#define MACRO4(REGS, FIRSTPROJ) MACRO4_I(REGS, FIRSTPROJ)

    // drain compiler-issued (weight) loads so asm vm counts are exact
    asm volatile("s_waitcnt vmcnt(0)" ::: "memory");

    LOADM(AREGS)                       // L0
    LOADM(BREGS)                       // L1
    LOADM(CREGS)                       // L2
    WAITM(16, AREGS); MACRO4(AREGS, false)    // M0 (3 atomics: h_{-1}=0)
    LOADM(AREGS)                       // L3
    WAITM(19, BREGS); MACRO4(BREGS, true)     // M1 (4 atomics)
    LOADM(BREGS)                       // L4
    WAITM(23, CREGS); MACRO4(CREGS, true)     // M2

    for (int i = 0; i < 339; ++i) {    // M3..M1019, loads L5..L1021
        LOADM(CREGS) WAITM(24, AREGS); MACRO4(AREGS, true)
        LOADM(AREGS) WAITM(24, BREGS); MACRO4(BREGS, true)
        LOADM(BREGS) WAITM(24, CREGS); MACRO4(CREGS, true)
    }
    LOADM(CREGS)                       // L1022
    WAITM(24, AREGS); MACRO4(AREGS, true)     // M1020
    LOADM(AREGS)                       // L1023
    WAITM(24, BREGS); MACRO4(BREGS, true)     // M1021
    WAITM(16, CREGS); MACRO4(CREGS, true)     // M1022
    WAITM(8,  AREGS); MACRO4(AREGS, true)     // M1023

#undef LOADM
#undef LOADM_I
#undef MACRO4
#undef MACRO4_I
#undef WAITM
#undef WAITM_I
#undef AREGS
#undef BREGS
#undef CREGS

    // tail: projection of the final h (all lanes, halved Wcp)
    {
        float pa = h * Wcp[0];
        pa = fmaf(rorN<1>(h), Wcp[1], pa);
        pa = fmaf(rorN<2>(h), Wcp[2], pa);
        pa = fmaf(rorN<3>(h), Wcp[3], pa);
        pa = fmaf(rorN<4>(h), Wcp[4], pa);
        pa = fmaf(rorN<5>(h), Wcp[5], pa);
        pa = fmaf(rorN<6>(h), Wcp[6], pa);
        pa = fmaf(rorN<7>(h), Wcp[7], pa);
        aatomic(wp, pa);
    }
}

__global__ __launch_bounds__(64, 1)
void lstm_rec_kernel(const float* __restrict__ x,
                     const float* __restrict__ WihF, const float* __restrict__ WhhF,
                     const float* __restrict__ bF,
                     const float* __restrict__ WihB, const float* __restrict__ WhhB,
                     const float* __restrict__ bB,
                     const float* __restrict__ Wp,
                     float* __restrict__ y)
{
    if (blockIdx.x < 64)
        rec_body<1 >(x, WihF, WhhF, bF, Wp, 0, y, 4 * (int)blockIdx.x);
    else
        rec_body<-1>(x, WihB, WhhB, bB, Wp, 8, y, 4 * ((int)blockIdx.x - 64));
}

extern "C" void kernel_launch(void* const* d_in, const int* in_sizes, int n_in,
                              void* d_out, int out_size, void* d_ws, size_t ws_size,
                              hipStream_t stream)
{
    const float* x     = (const float*)d_in[0];
    const float* Wih1f = (const float*)d_in[1];
    const float* Whh1f = (const float*)d_in[2];
    const float* b1f   = (const float*)d_in[3];
    const float* Wih1b = (const float*)d_in[4];
    const float* Whh1b = (const float*)d_in[5];
    const float* b1b   = (const float*)d_in[6];
    const float* Wih2f = (const float*)d_in[7];
    const float* Whh2f = (const float*)d_in[8];
    const float* b2f   = (const float*)d_in[9];
    const float* Wih2b = (const float*)d_in[10];
    const float* Whh2b = (const float*)d_in[11];
    const float* b2b   = (const float*)d_in[12];
    const float* W1    = (const float*)d_in[13];
    const float* bl1   = (const float*)d_in[14];
    const float* W2    = (const float*)d_in[15];
    const float* bl2   = (const float*)d_in[16];

    float* out = (float*)d_out;
    float* y1  = (float*)d_ws;   // [B,T,8] fp32 = 32 MB (proven-safe ws budget)

    const int BT = B_SZ * T_LEN;

    init_bias_kernel<<<BT / 256, 256, 0, stream>>>(bl1, bl2, y1, out);

    lstm_rec_kernel<<<128, 64, 0, stream>>>(x, Wih1f, Whh1f, b1f,
                                            Wih1b, Whh1b, b1b, W1, y1);

    lstm_rec_kernel<<<128, 64, 0, stream>>>(y1, Wih2f, Whh2f, b2f,
                                            Wih2b, Whh2b, b2b, W2, out);
}